// Round 8
// baseline (346.625 us; speedup 1.0000x reference)
//
#include <hip/hip_runtime.h>
#include <stdint.h>

#define N_NODES 100000
#define D_FEAT  128
#define N_EDGES 500000
#define HIDDEN  256
#define EPT     32                                   // edges per tile
#define NTILES  (N_EDGES / EPT)                      // 15625, exact
#define GRID_MAIN 768                                // 3 blocks/CU

typedef __bf16 bf16x8 __attribute__((ext_vector_type(8)));
typedef __bf16 bf16x4 __attribute__((ext_vector_type(4)));
typedef float  f32x4  __attribute__((ext_vector_type(4)));

__device__ __forceinline__ void gld_lds16(const unsigned short* g, unsigned char* l) {
  __builtin_amdgcn_global_load_lds(
      (const __attribute__((address_space(1))) unsigned int*)g,
      (__attribute__((address_space(3))) unsigned int*)l, 16, 0, 0);
}

__device__ __forceinline__ bf16x8 cvt8(f32x4 lo, f32x4 hi) {
  bf16x8 r;
  r[0] = (__bf16)lo[0]; r[1] = (__bf16)lo[1]; r[2] = (__bf16)lo[2]; r[3] = (__bf16)lo[3];
  r[4] = (__bf16)hi[0]; r[5] = (__bf16)hi[1]; r[6] = (__bf16)hi[2]; r[7] = (__bf16)hi[7-4];
  r[7] = (__bf16)hi[3];
  return r;
}

// z (f32) -> bf16, vectorized
__global__ void cvt_z(const float* __restrict__ src, unsigned short* __restrict__ dst, int n4) {
  int i = blockIdx.x * blockDim.x + threadIdx.x;
  const int stride = gridDim.x * blockDim.x;
  for (; i < n4; i += stride) {
    const f32x4 v = ((const f32x4*)src)[i];
    bf16x4 o;
    o[0] = (__bf16)v[0]; o[1] = (__bf16)v[1]; o[2] = (__bf16)v[2]; o[3] = (__bf16)v[3];
    ((bf16x4*)dst)[i] = o;
  }
}

// xT = relu(W1 * concatT + b1); out = sigmoid(w2 . x + b2)
// 4 waves/block; wave w owns hidden rows [64w, 64w+64) (a[4][8] resident),
// covers all 32 edges. K-major LDS unit: sbuf[c*1024 + l*16].
// Triple buffer, ONE barrier/tile, counted vmcnt(7), 3 blocks/CU (12 waves).
__global__ __launch_bounds__(256, 3)
void mlp_main(const int* __restrict__ eidx,
              const unsigned short* __restrict__ z16,   // [N_NODES][128] bf16
              const float* __restrict__ w1f,            // [256][256] f32
              const float* __restrict__ b1,
              const float* __restrict__ w2g,
              const float* __restrict__ b2,
              float* __restrict__ out,
              float* __restrict__ dump) {
  __shared__ unsigned char sbuf[3][EPT * 512];          // 3 x 16 KiB
  __shared__ float red[2][4][40];                       // parity x wave x edge(pad)

  const int tid  = threadIdx.x;
  const int w    = tid >> 6;         // wave 0..3 (hidden group of 64)
  const int l    = tid & 63;
  const int l15  = l & 15;
  const int l31  = l & 31;
  const int g    = l >> 4;           // k-slice group 0..3
  const int half = w >> 1;           // staging half: 0 = row node, 1 = col node

  const int is64 = (eidx[1] == 0 && eidx[3] == 0 && eidx[5] == 0);
  const float b2v = b2[0];
  const int estride = is64 ? 6 : 3;
  const int eoff    = is64 ? (2 + 2 * half) : (1 + half);

  // ---- A fragments (W1, f32 -> bf16), resident: 128 regs ----
  // A[n][k]: n = w*64 + nt*16 + (l&15), k = ks*32 + g*8 .. +7
  bf16x8 a[4][8];
  #pragma unroll
  for (int nt = 0; nt < 4; ++nt) {
    const int n = w * 64 + nt * 16 + l15;
    #pragma unroll
    for (int ks = 0; ks < 8; ++ks) {
      const int k = ks * 32 + g * 8;
      const f32x4 lo = *(const f32x4*)(w1f + n * 256 + k);
      const f32x4 hi = *(const f32x4*)(w1f + n * 256 + k + 4);
      bf16x8 v;
      v[0] = (__bf16)lo[0]; v[1] = (__bf16)lo[1]; v[2] = (__bf16)lo[2]; v[3] = (__bf16)lo[3];
      v[4] = (__bf16)hi[0]; v[5] = (__bf16)hi[1]; v[6] = (__bf16)hi[2]; v[7] = (__bf16)hi[3];
      a[nt][ks] = v;
    }
  }
  // bias / fc2 weights for this lane's accumulator rows (C/D row = g*4 + r)
  f32x4 b1v[4], w2v[4];
  #pragma unroll
  for (int nt = 0; nt < 4; ++nt) {
    const int nb = w * 64 + nt * 16 + g * 4;
    b1v[nt] = *(const f32x4*)(b1 + nb);
    w2v[nt] = *(const f32x4*)(w2g + nb);
  }

  // per-lane node index (this wave's half) for tile t; lane -> edge l&31
  auto ldidx = [&](int t) -> int {
    int e = t * EPT + l31;
    if (e > N_EDGES - 1) e = N_EDGES - 1;
    return eidx[e * estride + eoff];
  };
  // stage one tile: wave w issues chunks 4w..4w+3 (1 KiB each, linear dest)
  auto stage = [&](int buf, int iv) {
    const unsigned short* src = z16 + (size_t)iv * D_FEAT;
    #pragma unroll
    for (int j = 0; j < 4; ++j) {
      const int c = 4 * w + j;                 // chunks 0-7: row, 8-15: col
      gld_lds16(src + ((c & 7) << 4) + ((l >> 5) << 3), &sbuf[buf][c << 10]);
    }
  };

  // cross-wave sum + sigmoid for a finished tile; always ONE store per lane<8
  auto emit = [&](int tile, int par, bool real) {
    const int m  = 8 * w + (l & 7);            // this wave's 8 edges
    float v = red[par][(l >> 3) & 3][m];       // lane group = source wave
    v += __shfl_xor(v, 8);
    v += __shfl_xor(v, 16);
    const float s = 1.f / (1.f + __expf(-(v + b2v)));
    float* dst = real ? (out + tile * EPT + m) : (dump + blockIdx.x * EPT + m);
    if (l < 8) *dst = s;
  };

  // ---- prologue: stage t0; prefetch idx t0+G, t0+2G; pass-visible drain ----
  const int t0 = blockIdx.x;
  stage(0, ldidx(t0));
  int iv_b = ldidx(t0 + GRID_MAIN);
  int iv_c = ldidx(t0 + 2 * GRID_MAIN);
  __builtin_amdgcn_s_waitcnt(0);               // full drain (compiler-visible)

  int it = 0, cb = 0;
  for (int t = t0; t < NTILES; t += GRID_MAIN, ++it) {
    // 1) stage tile t+1 (iv_b loaded 2 iters ago -> compiler wait is counted)
    int cn = cb + 1; if (cn == 3) cn = 0;
    stage(cn, iv_b);
    // 2) idx prefetch for t+3
    const int iv_d = ldidx(t + 3 * GRID_MAIN);
    // 3) counted wait: 6 vmem ops/iter {stage 4, idx 1, store 1}; at this
    //    point newest 7 = {idx(t+2), store(t-2), stage(t+1) x4, idx(t+3)} ->
    //    vmcnt(7) retires stage(t) exactly. NEVER 0 in loop.
    asm volatile("s_waitcnt vmcnt(7) lgkmcnt(0)" ::: "memory");
    __builtin_amdgcn_sched_barrier(0);
    __builtin_amdgcn_s_barrier();
    __builtin_amdgcn_sched_barrier(0);

    // 4) deferred output for tile t-1 (dummy store to dump at it==0)
    emit(t - GRID_MAIN, (it - 1) & 1, it != 0);

    // 5) MFMA: D[n][m] += sum_k A[n][k] * F[m][k] on buf cb
    f32x4 acc[4][2];
    #pragma unroll
    for (int nt = 0; nt < 4; ++nt) {
      acc[nt][0] = (f32x4){0.f, 0.f, 0.f, 0.f};
      acc[nt][1] = (f32x4){0.f, 0.f, 0.f, 0.f};
    }
    const unsigned char* sb = &sbuf[cb][0];
    const int off0 = ((g >> 1) << 10) + ((g & 1) << 9) + (l15 << 4);
    #pragma unroll
    for (int ks = 0; ks < 8; ++ks) {
      bf16x8 bf[2];
      #pragma unroll
      for (int ct = 0; ct < 2; ++ct)           // conflict-free ds_read_b128
        bf[ct] = *(const bf16x8*)(sb + (ks << 11) + (ct << 8) + off0);
      __builtin_amdgcn_s_setprio(1);
      #pragma unroll
      for (int nt = 0; nt < 4; ++nt)
        #pragma unroll
        for (int ct = 0; ct < 2; ++ct)
          acc[nt][ct] = __builtin_amdgcn_mfma_f32_16x16x32_bf16(
              a[nt][ks], bf[ct], acc[nt][ct], 0, 0, 0);
      __builtin_amdgcn_s_setprio(0);
    }

    // 6) epilogue: bias + relu + fc2 partial dot -> red[it&1]
    float p[2] = {0.f, 0.f};
    #pragma unroll
    for (int nt = 0; nt < 4; ++nt) {
      #pragma unroll
      for (int r = 0; r < 4; ++r) {
        const float bb = b1v[nt][r], ww = w2v[nt][r];
        #pragma unroll
        for (int ct = 0; ct < 2; ++ct) {
          float x = acc[nt][ct][r] + bb;       // n = w*64+nt*16+g*4+r
          x = fmaxf(x, 0.f);
          p[ct] = fmaf(x, ww, p[ct]);
        }
      }
    }
    #pragma unroll
    for (int ct = 0; ct < 2; ++ct) {           // sum over 4 g-groups
      p[ct] += __shfl_xor(p[ct], 16);
      p[ct] += __shfl_xor(p[ct], 32);
    }
    if (l < 16) {
      red[it & 1][w][l15]      = p[0];
      red[it & 1][w][16 + l15] = p[1];
    }

    iv_b = iv_c; iv_c = iv_d; cb = cn;
  }

  // ---- tail: output last tile ----
  asm volatile("s_waitcnt lgkmcnt(0)" ::: "memory");
  __builtin_amdgcn_s_barrier();
  emit(t0 + (it - 1) * GRID_MAIN, (it - 1) & 1, true);
}

extern "C" void kernel_launch(void* const* d_in, const int* in_sizes, int n_in,
                              void* d_out, int out_size, void* d_ws, size_t ws_size,
                              hipStream_t stream) {
  const float* z    = (const float*)d_in[0];
  const int*   eidx = (const int*)d_in[1];
  const float* fc1w = (const float*)d_in[2];
  const float* fc1b = (const float*)d_in[3];
  const float* fc2w = (const float*)d_in[4];
  const float* fc2b = (const float*)d_in[5];
  float* out = (float*)d_out;

  unsigned short* z16 = (unsigned short*)d_ws;       // 25.6 MB bf16 copy of z
  float* dump = (float*)((unsigned char*)d_ws + 25600000);  // 98 KB scratch

  cvt_z<<<2048, 256, 0, stream>>>(z, z16, N_NODES * D_FEAT / 4);
  mlp_main<<<GRID_MAIN, 256, 0, stream>>>(eidx, z16, fc1w, fc1b, fc2w, fc2b,
                                          out, dump);
}